// Round 2
// baseline (93.486 us; speedup 1.0000x reference)
//
#include <hip/hip_runtime.h>

// Problem dims (fixed by setup_inputs): S=256, BT=32, D=128, N=128, O=128
#define S_DIM 256
#define BT_DIM 32
#define D_DIM 128
#define N_DIM 128
#define O_DIM 128
#define SB (S_DIM * BT_DIM)   // 8192 flattened (s,b) rows

// out[r][n] = sum_d A[r][d] * W[n][d]
// A: [SB][D_DIM] row-major, W: [N_DIM][D_DIM] row-major (i.e. computes A @ W^T)
// Block: 256 threads handles 16 rows x 128 cols.
__global__ __launch_bounds__(256) void gemm_rowdot(const float* __restrict__ A,
                                                   const float* __restrict__ W,
                                                   float* __restrict__ out) {
    __shared__ float xs[16][D_DIM];   // 8 KB
    const int t = threadIdx.x;
    const int r0 = blockIdx.x * 16;

    // Stage 16x128 fp32 tile of A: 512 float4 loads, 2 per thread, coalesced.
    const float4* A4 = reinterpret_cast<const float4*>(A + (size_t)r0 * D_DIM);
    float4* xs4 = reinterpret_cast<float4*>(&xs[0][0]);
    xs4[t] = A4[t];
    xs4[t + 256] = A4[t + 256];
    __syncthreads();

    const int n  = t & 127;   // output column
    const int rh = t >> 7;    // row half: 0 -> rows 0..7, 1 -> rows 8..15

    float acc[8] = {0.f, 0.f, 0.f, 0.f, 0.f, 0.f, 0.f, 0.f};
    const float4* W4 = reinterpret_cast<const float4*>(W + (size_t)n * D_DIM);

    #pragma unroll 4
    for (int d4 = 0; d4 < D_DIM / 4; ++d4) {
        const float4 w = W4[d4];           // L2-resident (W is 64 KB total)
        #pragma unroll
        for (int rr = 0; rr < 8; ++rr) {
            // All lanes in a wave share rh -> same LDS address -> broadcast.
            const float4 xv = *reinterpret_cast<const float4*>(&xs[rh * 8 + rr][d4 * 4]);
            acc[rr] = fmaf(xv.x, w.x, acc[rr]);
            acc[rr] = fmaf(xv.y, w.y, acc[rr]);
            acc[rr] = fmaf(xv.z, w.z, acc[rr]);
            acc[rr] = fmaf(xv.w, w.w, acc[rr]);
        }
    }

    #pragma unroll
    for (int rr = 0; rr < 8; ++rr)
        out[(size_t)(r0 + rh * 8 + rr) * N_DIM + n] = acc[rr];  // coalesced: n contiguous
}

// Per-(b,n) linear scan over time: h_t = lam*h_{t-1} + gamma*Bx_t.
// 4096 threads total, 64 blocks x 64 threads -> spreads over 64 CUs.
// Also writes hT (final h) to d_out tail.
__global__ __launch_bounds__(64) void scan_kernel(const float* __restrict__ Bx,
                                                  const float* __restrict__ lambda_log,
                                                  float* __restrict__ hs,
                                                  float* __restrict__ hT) {
    const int idx = blockIdx.x * 64 + threadIdx.x;  // (b,n): b=idx/128, n=idx%128
    const int n = idx & 127;

    const float ll    = lambda_log[n];
    const float lam   = expf(-expf(ll));
    const float gamma = sqrtf(1.0f - lam * lam + 1e-7f);

    float h = 0.0f;
    const int stride = BT_DIM * N_DIM;  // 4096
    for (int t0 = 0; t0 < S_DIM; t0 += 8) {
        float bx[8];
        #pragma unroll
        for (int k = 0; k < 8; ++k)
            bx[k] = Bx[(size_t)(t0 + k) * stride + idx];   // 8 independent loads in flight
        #pragma unroll
        for (int k = 0; k < 8; ++k) {
            h = fmaf(lam, h, gamma * bx[k]);
            hs[(size_t)(t0 + k) * stride + idx] = h;
        }
    }
    hT[idx] = h;
}

extern "C" void kernel_launch(void* const* d_in, const int* in_sizes, int n_in,
                              void* d_out, int out_size, void* d_ws, size_t ws_size,
                              hipStream_t stream) {
    const float* x          = (const float*)d_in[0];  // [S][BT][D]
    const float* lambda_log = (const float*)d_in[1];  // [N]
    const float* B          = (const float*)d_in[2];  // [N][D]
    const float* C          = (const float*)d_in[3];  // [O][N]

    float* out = (float*)d_out;                 // outputs [S][BT][O] then hT [BT][N]
    float* Bx  = (float*)d_ws;                  // [SB][N]  = 4 MB
    float* hs  = Bx + (size_t)SB * N_DIM;       // [SB][N]  = 4 MB

    // 1) Bx = X @ B^T   (rows = flattened (s,b))
    gemm_rowdot<<<SB / 16, 256, 0, stream>>>(x, B, Bx);

    // 2) time scan per (b,n); writes hs and hT
    scan_kernel<<<(BT_DIM * N_DIM) / 64, 64, 0, stream>>>(
        Bx, lambda_log, hs, out + (size_t)SB * O_DIM);

    // 3) outputs = hs @ C^T
    gemm_rowdot<<<SB / 16, 256, 0, stream>>>(hs, C, out);
}